// Round 1
// baseline (139.435 us; speedup 1.0000x reference)
//
#include <hip/hip_runtime.h>
#include <hip/hip_bf16.h>

#define MD 128   // D
#define KC 8     // K capsules
#define KD 16    // DD
#define MN 16    // M neighbors

__device__ __forceinline__ float bf2f(unsigned short u) {
    union { unsigned int i; float f; } c;
    c.i = ((unsigned int)u) << 16;
    return c.f;
}

template<bool BF>
__device__ __forceinline__ float2 load2(const void* base, int off) {
    if (BF) {
        unsigned int u = *(const unsigned int*)((const unsigned short*)base + off);
        float2 r;
        r.x = bf2f((unsigned short)(u & 0xffffu));
        r.y = bf2f((unsigned short)(u >> 16));
        return r;
    } else {
        return *(const float2*)((const float*)base + off);
    }
}

template<bool BF>
__device__ __forceinline__ float load1(const void* base, int off) {
    if (BF) return bf2f(((const unsigned short*)base)[off]);
    return ((const float*)base)[off];
}

__device__ __forceinline__ void cas(float& x, float& y) {
    float lo = fminf(x, y), hi = fmaxf(x, y);
    x = lo; y = hi;
}

// full odd-even transposition sort of 17 values, static indices -> registers
__device__ __forceinline__ float median17(float a[17]) {
    #pragma unroll
    for (int r = 0; r < 17; ++r) {
        #pragma unroll
        for (int i = (r & 1); i + 1 < 17; i += 2) cas(a[i], a[i + 1]);
    }
    return a[8];  // (17-1)//2 lower median == true median
}

__device__ __forceinline__ float rsum_g(float v) {  // sum over 8-lane capsule group
    v += __shfl_xor(v, 1); v += __shfl_xor(v, 2); v += __shfl_xor(v, 4);
    return v;
}
__device__ __forceinline__ float rsum_x(float v) {  // sum across the 8 capsules
    v += __shfl_xor(v, 8); v += __shfl_xor(v, 16); v += __shfl_xor(v, 32);
    return v;
}
__device__ __forceinline__ float rmax_x(float v) {
    v = fmaxf(v, __shfl_xor(v, 8));
    v = fmaxf(v, __shfl_xor(v, 16));
    v = fmaxf(v, __shfl_xor(v, 32));
    return v;
}

// flag[0] = 1 if h is bf16, 0 if f32. Reading f32 bits as bf16 exposes random
// exponents in the low halves -> max blows past 1000 almost surely.
__global__ void detect_dtype(const unsigned short* __restrict__ h, int* __restrict__ flag) {
    int l = threadIdx.x;
    float m = 0.f;
    for (int i = l; i < 1024; i += 64) {
        float v = bf2f(h[i]);
        v = (v != v) ? 1e30f : fabsf(v);
        m = fmaxf(m, v);
    }
    #pragma unroll
    for (int off = 1; off < 64; off <<= 1) m = fmaxf(m, __shfl_xor(m, off));
    if (l == 0) flag[0] = (m < 1000.0f) ? 1 : 0;
}

template<bool BF>
__global__ __launch_bounds__(256)
void attn_fwd(const void* __restrict__ hraw,
              const int* __restrict__ nbr,
              const void* __restrict__ qry,
              const void* __restrict__ keyw,
              const int* __restrict__ iterat_p,
              const int* __restrict__ flag_p,
              void* __restrict__ out,
              int n_nodes)
{
    if (flag_p[0] != (BF ? 1 : 0)) return;  // whole block exits together (no barrier yet)

    const int tid = threadIdx.x;
    const int wid = tid >> 6;       // wave in block: 0..3 (one node each)
    const int l   = tid & 63;       // lane
    const int k   = l >> 3;         // capsule 0..7
    const int j8  = l & 7;          // lane within capsule group
    const int d0  = j8 * 2;         // this lane's 2 dims of the capsule
    int n = blockIdx.x * 4 + wid;
    if (n >= n_nodes) n = n_nodes - 1;  // duplicate work, identical writes: benign

    __shared__ float qry_s[256], qryT_s[256], key_s[256];
    __shared__ float hc_s[4][KC * 17], kk_s[4][KC * 17];  // stride 17: bank-spread

    {   // stage query / query^T / key_w in LDS (256 threads, 1 elem each)
        float qv = load1<BF>(qry, tid);
        float kv = load1<BF>(keyw, tid);
        qry_s[tid] = qv;
        qryT_s[(tid & 15) * 16 + (tid >> 4)] = qv;
        key_s[tid] = kv;
    }

    // ---- h row, per-capsule normalize ----
    float2 hp = load2<BF>(hraw, n * MD + 2 * l);
    float ss  = rsum_g(hp.x * hp.x + hp.y * hp.y);
    float inv = 1.0f / fmaxf(sqrtf(ss), 1e-12f);
    float hc0 = hp.x * inv, hc1 = hp.y * inv;
    hc_s[wid][k * 17 + d0]     = hc0;
    hc_s[wid][k * 17 + d0 + 1] = hc1;
    __syncthreads();

    // ---- q = hc@query, kk = hc@key ----
    float q0 = 0, q1 = 0, kk0 = 0, kk1 = 0;
    #pragma unroll
    for (int e = 0; e < 16; ++e) {
        float hce = hc_s[wid][k * 17 + e];
        q0  += hce * qry_s[e * 16 + d0];
        q1  += hce * qry_s[e * 16 + d0 + 1];
        kk0 += hce * key_s[e * 16 + d0];
        kk1 += hce * key_s[e * 16 + d0 + 1];
    }
    kk_s[wid][k * 17 + d0]     = kk0;
    kk_s[wid][k * 17 + d0 + 1] = kk1;
    __syncthreads();

    // ---- att = softmax_k( dot(q[k], kk[k]) ) ----
    float logit = rsum_g(q0 * kk0 + q1 * kk1);
    float mx  = rmax_x(logit);
    float ex  = expf(logit - mx);
    float att = ex / rsum_x(ex);

    // ---- w[k][e] = sum_f query[e][f]*kk[k][f]  (folds qs@kk^T diag) ----
    float w0 = 0, w1 = 0;
    #pragma unroll
    for (int f = 0; f < 16; ++f) {
        float kf = kk_s[wid][k * 17 + f];
        w0 += qryT_s[f * 16 + d0]     * kf;
        w1 += qryT_s[f * 16 + d0 + 1] * kf;
    }

    // ---- neighbor gather: keep all 16 rows' pair in regs for the median ----
    float a0[17], a1[17];
    float nbs0 = 0, nbs1 = 0, s20 = 0, s21 = 0;
    #pragma unroll
    for (int m = 0; m < MN; ++m) {
        int idx = nbr[n * MN + m];
        float2 v = load2<BF>(hraw, idx * MD + 2 * l);
        a0[m] = v.x; a1[m] = v.y;
        nbs0 += v.x; nbs1 += v.y;
        s20 += v.x * v.x; s21 += v.y * v.y;
    }
    a0[16] = hc0; a1[16] = hc1;
    s20 += hc0 * hc0; s21 += hc1 * hc1;

    // diag[k] = (sum_m nb[m,k]) . w[k]
    float dg = rsum_g(nbs0 * w0 + nbs1 * w1);

    // middle = median over 17 of normalized-by-column values
    float mid0 = median17(a0) / fmaxf(sqrtf(s20), 1e-12f);
    float mid1 = median17(a1) / fmaxf(sqrtf(s21), 1e-12f);

    // cov_d = sum_k diag[k] * (hc[k,d]-middle[k,d])^2   (i-independent)
    float t0 = hc0 - mid0, t1 = hc1 - mid1;
    float c0 = rsum_x(dg * t0 * t0);
    float c1 = rsum_x(dg * t1 * t1);

    // dets/left with exact NaN semantics of the reference
    float lr0 = logf(c0); lr0 = (lr0 != lr0) ? 1e-6f : lr0;
    float lr1 = logf(c1); lr1 = (lr1 != lr1) ? 1e-6f : lr1;
    float ls  = rsum_g(logf(lr0) + logf(lr1));
    float dets = expf(ls);
    const float coef = 5.822108e-7f;  // 1/sqrt((2*pi)^16 / 2)
    float left = coef / sqrtf(dets + 1e-6f);

    // ---- iterative routing ----
    float ix0 = rsum_x(att * hc0);
    float ix1 = rsum_x(att * hc1);

    const int iterat = iterat_p[0];
    for (int it = 0; it < iterat; ++it) {
        float df0 = ix0 - hc0, df1 = ix1 - hc1;
        float rs  = rsum_g(c0 * df0 * df0 + c1 * df1 * df1);
        float right = expf(-0.5f * rs);
        float prob  = left * right;
        float p2    = rsum_x(prob * prob);
        float pn    = prob / fmaxf(sqrtf(p2), 1e-12f);
        pn = (pn != pn) ? 1e-6f : pn;
        float ap   = att * pn;
        float num0 = rsum_x(ap * hc0);
        float num1 = rsum_x(ap * hc1);
        float den  = rsum_x(ap);
        float rr   = 1.0f / (den + 1e-9f);
        ix0 = num0 * rr; ix1 = num1 * rr;
    }

    // ---- x = normalize(ix) ----
    float xs   = rsum_g(ix0 * ix0 + ix1 * ix1);
    float xinv = 1.0f / fmaxf(sqrtf(xs), 1e-12f);
    float x0 = ix0 * xinv, x1 = ix1 * xinv;

    if (BF) {
        __hip_bfloat16* o = (__hip_bfloat16*)out;
        if (l < 8) {
            o[n * KD + d0]     = __float2bfloat16(x0);
            o[n * KD + d0 + 1] = __float2bfloat16(x1);
        }
        if (j8 == 0) o[n_nodes * KD + n * KC + k] = __float2bfloat16(att);
    } else {
        float* o = (float*)out;
        if (l < 8) {
            float2 xv; xv.x = x0; xv.y = x1;
            *(float2*)(o + n * KD + d0) = xv;
        }
        if (j8 == 0) o[n_nodes * KD + n * KC + k] = att;
    }
}

extern "C" void kernel_launch(void* const* d_in, const int* in_sizes, int n_in,
                              void* d_out, int out_size, void* d_ws, size_t ws_size,
                              hipStream_t stream) {
    const void* h    = d_in[0];
    const int*  nbr  = (const int*)d_in[1];
    const void* qry  = d_in[2];
    const void* keyw = (const void*)d_in[3];
    const int*  iterat_p = (const int*)d_in[4];
    // d_in[5] = max_iter (unused by reference forward)

    int n_nodes = in_sizes[0] / MD;
    int* flag = (int*)d_ws;

    detect_dtype<<<1, 64, 0, stream>>>((const unsigned short*)h, flag);

    int blocks = (n_nodes + 3) / 4;
    attn_fwd<true ><<<blocks, 256, 0, stream>>>(h, nbr, qry, keyw, iterat_p, flag, d_out, n_nodes);
    attn_fwd<false><<<blocks, 256, 0, stream>>>(h, nbr, qry, keyw, iterat_p, flag, d_out, n_nodes);
}

// Round 2
// 109.783 us; speedup vs baseline: 1.2701x; 1.2701x over previous
//
#include <hip/hip_runtime.h>
#include <hip/hip_bf16.h>

#define MD 128   // D
#define KC 8     // K capsules
#define KD 16    // DD
#define MN 16    // M neighbors
#define HS 18    // LDS stride for per-capsule 16-vectors (even, conflict-spread)

__device__ __forceinline__ float2 unpack_bf(unsigned int u) {
    union { unsigned int i; float f; } a, b;
    a.i = u << 16; b.i = u & 0xffff0000u;
    float2 r; r.x = a.f; r.y = b.f; return r;
}
__device__ __forceinline__ float bf2f1(unsigned short u) {
    union { unsigned int i; float f; } c; c.i = ((unsigned int)u) << 16; return c.f;
}
template<bool BF>
__device__ __forceinline__ float load1(const void* base, int off) {
    if (BF) return bf2f1(((const unsigned short*)base)[off]);
    return ((const float*)base)[off];
}

__device__ __forceinline__ float fast_rsq(float x) { return __builtin_amdgcn_rsqf(x); }
__device__ __forceinline__ float fast_rcp(float x) { return __builtin_amdgcn_rcpf(x); }

__device__ __forceinline__ void cas(float& x, float& y) {
    float lo = fminf(x, y), hi = fmaxf(x, y);
    x = lo; y = hi;
}

// Batcher odd-even mergesort, 8 elements, 19 CAS
__device__ __forceinline__ void sort8(float a[8]) {
    cas(a[0],a[1]); cas(a[2],a[3]); cas(a[4],a[5]); cas(a[6],a[7]);
    cas(a[0],a[2]); cas(a[1],a[3]); cas(a[4],a[6]); cas(a[5],a[7]);
    cas(a[1],a[2]); cas(a[5],a[6]);
    cas(a[0],a[4]); cas(a[2],a[6]); cas(a[2],a[4]);
    cas(a[1],a[5]); cas(a[3],a[7]); cas(a[3],a[5]);
    cas(a[1],a[2]); cas(a[3],a[4]); cas(a[5],a[6]);
}

// median of {u[0..7]} ∪ {v[0..7]} ∪ {x}, u and v each sorted ascending.
// b7/b8 (8th/9th smallest of 16) via t_k = max_{i+j=k} min(u_i, v_j);
// median17 = med3(x, b7, b8)  (= clamp of x into the middle pair).
__device__ __forceinline__ float med_insert(const float u[8], const float v[8], float x) {
    float t7 =            fminf(u[7], v[0]);
    t7 = fmaxf(t7, fminf(u[6], v[1]));
    t7 = fmaxf(t7, fminf(u[5], v[2]));
    t7 = fmaxf(t7, fminf(u[4], v[3]));
    t7 = fmaxf(t7, fminf(u[3], v[4]));
    t7 = fmaxf(t7, fminf(u[2], v[5]));
    t7 = fmaxf(t7, fminf(u[1], v[6]));
    t7 = fmaxf(t7, fminf(u[0], v[7]));
    float t8 = fmaxf(u[0], v[0]);          // i=0 or j=0 with OOR partner
    t8 = fmaxf(t8, fminf(u[7], v[1]));
    t8 = fmaxf(t8, fminf(u[6], v[2]));
    t8 = fmaxf(t8, fminf(u[5], v[3]));
    t8 = fmaxf(t8, fminf(u[4], v[4]));
    t8 = fmaxf(t8, fminf(u[3], v[5]));
    t8 = fmaxf(t8, fminf(u[2], v[6]));
    t8 = fmaxf(t8, fminf(u[1], v[7]));
    return __builtin_amdgcn_fmed3f(x, t7, t8);
}

__device__ __forceinline__ float rsum_g(float v) {  // sum over 8-lane capsule group
    v += __shfl_xor(v, 1); v += __shfl_xor(v, 2); v += __shfl_xor(v, 4);
    return v;
}
__device__ __forceinline__ float rsum_x(float v) {  // sum across the 8 capsules
    v += __shfl_xor(v, 8); v += __shfl_xor(v, 16); v += __shfl_xor(v, 32);
    return v;
}
__device__ __forceinline__ float rmax_x(float v) {
    v = fmaxf(v, __shfl_xor(v, 8));
    v = fmaxf(v, __shfl_xor(v, 16));
    v = fmaxf(v, __shfl_xor(v, 32));
    return v;
}

// flag[0] = 1 if h is bf16, 0 if f32 (f32 bits read as bf16 expose huge exponents)
__global__ void detect_dtype(const unsigned short* __restrict__ h, int* __restrict__ flag) {
    int l = threadIdx.x;
    float m = 0.f;
    for (int i = l; i < 1024; i += 64) {
        float v = bf2f1(h[i]);
        v = (v != v) ? 1e30f : fabsf(v);
        m = fmaxf(m, v);
    }
    #pragma unroll
    for (int off = 1; off < 64; off <<= 1) m = fmaxf(m, __shfl_xor(m, off));
    if (l == 0) flag[0] = (m < 1000.0f) ? 1 : 0;
}

template<bool BF>
__global__ __launch_bounds__(256)
void attn_fwd(const void* __restrict__ hraw,
              const int* __restrict__ nbr,
              const void* __restrict__ qry,
              const void* __restrict__ keyw,
              const int* __restrict__ iterat_p,
              const int* __restrict__ flag_p,
              void* __restrict__ out,
              int n_nodes)
{
    if (flag_p[0] != (BF ? 1 : 0)) return;  // whole block exits together (no barrier yet)

    const int tid = threadIdx.x;
    const int wid = tid >> 6;
    const int l   = tid & 63;
    const int k   = l >> 3;
    const int j8  = l & 7;
    const int d0  = j8 * 2;
    int n = blockIdx.x * 4 + wid;
    if (n >= n_nodes) n = n_nodes - 1;
    const int n_s = __builtin_amdgcn_readfirstlane(n);  // wave-uniform -> SGPR bases

    __shared__ float qry_s[256], qryT_s[256], key_s[256];
    __shared__ float hc_s[4][KC * HS], kk_s[4][KC * HS];

    // neighbor indices: lane m (m<16) holds nbr[n,m]
    const int nbv = nbr[n_s * MN + (l & 15)];

    {   // stage query / query^T / key_w
        float qv = load1<BF>(qry, tid);
        float kv = load1<BF>(keyw, tid);
        qry_s[tid] = qv;
        qryT_s[(tid & 15) * 16 + (tid >> 4)] = qv;
        key_s[tid] = kv;
    }

    // ---- self row, per-capsule normalize ----
    float2 hp;
    if (BF) {
        const unsigned int* hw = (const unsigned int*)hraw + (size_t)n_s * (MD / 2);
        hp = unpack_bf(hw[l]);
    } else {
        const float2* hw = (const float2*)hraw + (size_t)n_s * (MD / 2);
        hp = hw[l];
    }
    float ss  = rsum_g(hp.x * hp.x + hp.y * hp.y);
    float inv = fast_rsq(fmaxf(ss, 1e-24f));     // == 1/max(sqrt(ss),1e-12)
    float hc0 = hp.x * inv, hc1 = hp.y * inv;
    hc_s[wid][k * HS + d0]     = hc0;
    hc_s[wid][k * HS + d0 + 1] = hc1;
    __syncthreads();   // covers Q/K staging (cross-wave); the only barrier

    // ---- issue all 16 neighbor row loads (SGPR base + lane offset) ----
    unsigned int rbits[16];
    float2 rows[16];
    if (BF) {
        const unsigned int* hw = (const unsigned int*)hraw;
        #pragma unroll
        for (int m = 0; m < MN; ++m) {
            int idx = __builtin_amdgcn_readlane(nbv, m);
            rbits[m] = hw[(size_t)idx * (MD / 2) + l];
        }
    } else {
        const float2* hw = (const float2*)hraw;
        #pragma unroll
        for (int m = 0; m < MN; ++m) {
            int idx = __builtin_amdgcn_readlane(nbv, m);
            rows[m] = hw[(size_t)idx * (MD / 2) + l];
        }
    }

    // ---- q = hc@query, kk = hc@key (overlaps gather latency) ----
    float q0 = 0, q1 = 0, kk0 = 0, kk1 = 0;
    #pragma unroll
    for (int e = 0; e < 16; e += 2) {
        float2 hpr = *(const float2*)&hc_s[wid][k * HS + e];
        float2 q0p = *(const float2*)&qry_s[e * 16 + d0];
        float2 q1p = *(const float2*)&qry_s[(e + 1) * 16 + d0];
        float2 k0p = *(const float2*)&key_s[e * 16 + d0];
        float2 k1p = *(const float2*)&key_s[(e + 1) * 16 + d0];
        q0  += hpr.x * q0p.x + hpr.y * q1p.x;
        q1  += hpr.x * q0p.y + hpr.y * q1p.y;
        kk0 += hpr.x * k0p.x + hpr.y * k1p.x;
        kk1 += hpr.x * k0p.y + hpr.y * k1p.y;
    }
    kk_s[wid][k * HS + d0]     = kk0;
    kk_s[wid][k * HS + d0 + 1] = kk1;   // same-wave RAW: lgkmcnt only, no barrier

    // ---- att = softmax_k( dot(q[k], kk[k]) ) ----
    float logit = rsum_g(q0 * kk0 + q1 * kk1);
    float mx  = rmax_x(logit);
    float ex  = __expf(logit - mx);
    float att = ex * fast_rcp(rsum_x(ex));

    // ---- w[k][e] = (Q · kk[k])[e] ----
    float w0 = 0, w1 = 0;
    #pragma unroll
    for (int f = 0; f < 16; f += 2) {
        float2 kp = *(const float2*)&kk_s[wid][k * HS + f];
        float2 qa = *(const float2*)&qryT_s[f * 16 + d0];
        float2 qb = *(const float2*)&qryT_s[(f + 1) * 16 + d0];
        w0 += qa.x * kp.x + qb.x * kp.y;
        w1 += qa.y * kp.x + qb.y * kp.y;
    }

    // ---- convert gathered rows; sums for diag and column norms ----
    float u0[8], v0[8], u1[8], v1[8];
    float nbs0 = 0, nbs1 = 0, s20 = 0, s21 = 0;
    #pragma unroll
    for (int m = 0; m < 8; ++m) {
        float2 t = BF ? unpack_bf(rbits[m]) : rows[m];
        u0[m] = t.x; u1[m] = t.y;
        nbs0 += t.x; nbs1 += t.y;
        s20 = fmaf(t.x, t.x, s20); s21 = fmaf(t.y, t.y, s21);
    }
    #pragma unroll
    for (int m = 0; m < 8; ++m) {
        float2 t = BF ? unpack_bf(rbits[m + 8]) : rows[m + 8];
        v0[m] = t.x; v1[m] = t.y;
        nbs0 += t.x; nbs1 += t.y;
        s20 = fmaf(t.x, t.x, s20); s21 = fmaf(t.y, t.y, s21);
    }
    s20 = fmaf(hc0, hc0, s20); s21 = fmaf(hc1, hc1, s21);

    // diag[k] = (sum_m nb[m,k]) . (Q kk[k])
    float dg = rsum_g(nbs0 * w0 + nbs1 * w1);

    // median over 17 (16 sorted-in-two-halves + hc), then / column norm
    sort8(u0); sort8(v0); sort8(u1); sort8(v1);
    float mid0 = med_insert(u0, v0, hc0) * fast_rsq(fmaxf(s20, 1e-24f));
    float mid1 = med_insert(u1, v1, hc1) * fast_rsq(fmaxf(s21, 1e-24f));

    // cov_d = sum_k diag[k]*(hc-mid)^2   (row-independent)
    float t0 = hc0 - mid0, t1 = hc1 - mid1;
    float c0 = rsum_x(dg * t0 * t0);
    float c1 = rsum_x(dg * t1 * t1);

    // dets/left with exact NaN semantics (v_log(neg)=NaN, v_log(0)=-inf)
    float lr0 = __logf(c0); lr0 = (lr0 != lr0) ? 1e-6f : lr0;
    float lr1 = __logf(c1); lr1 = (lr1 != lr1) ? 1e-6f : lr1;
    float ls   = rsum_g(__logf(lr0) + __logf(lr1));
    float dets = __expf(ls);
    const float coef = 5.822108e-7f;  // 1/sqrt((2*pi)^16 / 2)
    float left = coef * fast_rsq(dets + 1e-6f);

    // ---- iterative routing ----
    float ah0 = att * hc0, ah1 = att * hc1;
    float ix0 = rsum_x(ah0);
    float ix1 = rsum_x(ah1);

    const int iterat = iterat_p[0];
    for (int it = 0; it < iterat; ++it) {
        float df0 = ix0 - hc0, df1 = ix1 - hc1;
        float rs  = rsum_g(fmaf(c0 * df0, df0, c1 * df1 * df1));
        float prob = left * __expf(-0.5f * rs);
        float p2   = rsum_x(prob * prob);
        float pn   = prob * fast_rsq(fmaxf(p2, 1e-24f));  // ==prob/max(||p||,1e-12)
        pn = (pn != pn) ? 1e-6f : pn;
        float num0 = rsum_x(pn * ah0);
        float num1 = rsum_x(pn * ah1);
        float den  = rsum_x(att * pn);
        float rr   = fast_rcp(den + 1e-9f);
        ix0 = num0 * rr; ix1 = num1 * rr;
    }

    // ---- x = normalize(ix) ----
    float xs   = rsum_g(ix0 * ix0 + ix1 * ix1);
    float xinv = fast_rsq(fmaxf(xs, 1e-24f));
    float x0 = ix0 * xinv, x1 = ix1 * xinv;

    if (BF) {
        if (l < 8) {
            __hip_bfloat16 b0 = __float2bfloat16(x0), b1 = __float2bfloat16(x1);
            unsigned int w = ((unsigned int)(*(unsigned short*)&b1) << 16)
                           | (unsigned int)(*(unsigned short*)&b0);
            ((unsigned int*)out)[(size_t)n * (KD / 2) + j8] = w;
        }
        if (j8 == 0) {
            __hip_bfloat16 ba = __float2bfloat16(att);
            ((unsigned short*)out)[(size_t)n_nodes * KD + (size_t)n * KC + k] =
                *(unsigned short*)&ba;
        }
    } else {
        float* o = (float*)out;
        if (l < 8) {
            float2 xv; xv.x = x0; xv.y = x1;
            *(float2*)(o + (size_t)n * KD + d0) = xv;
        }
        if (j8 == 0) o[(size_t)n_nodes * KD + (size_t)n * KC + k] = att;
    }
}

extern "C" void kernel_launch(void* const* d_in, const int* in_sizes, int n_in,
                              void* d_out, int out_size, void* d_ws, size_t ws_size,
                              hipStream_t stream) {
    const void* h    = d_in[0];
    const int*  nbr  = (const int*)d_in[1];
    const void* qry  = d_in[2];
    const void* keyw = (const void*)d_in[3];
    const int*  iterat_p = (const int*)d_in[4];

    int n_nodes = in_sizes[0] / MD;
    int* flag = (int*)d_ws;

    detect_dtype<<<1, 64, 0, stream>>>((const unsigned short*)h, flag);

    int blocks = (n_nodes + 3) / 4;
    attn_fwd<true ><<<blocks, 256, 0, stream>>>(h, nbr, qry, keyw, iterat_p, flag, d_out, n_nodes);
    attn_fwd<false><<<blocks, 256, 0, stream>>>(h, nbr, qry, keyw, iterat_p, flag, d_out, n_nodes);
}

// Round 3
// 91.492 us; speedup vs baseline: 1.5240x; 1.1999x over previous
//
#include <hip/hip_runtime.h>
#include <hip/hip_bf16.h>

#define MD 128   // D
#define KC 8     // K capsules
#define KD 16    // DD
#define MN 16    // M neighbors
#define QS 20    // LDS row stride (floats): 16B-aligned, bank-spread

static __device__ __forceinline__ float lo_bf(unsigned int w){ union{unsigned int i;float f;}c; c.i=w<<16;        return c.f; }
static __device__ __forceinline__ float hi_bf(unsigned int w){ union{unsigned int i;float f;}c; c.i=w&0xffff0000u; return c.f; }
static __device__ __forceinline__ float bf2f1(unsigned short u){ union{unsigned int i;float f;}c; c.i=((unsigned int)u)<<16; return c.f; }

template<bool BF>
static __device__ __forceinline__ float load1(const void* base, int off) {
    if (BF) return bf2f1(((const unsigned short*)base)[off]);
    return ((const float*)base)[off];
}

static __device__ __forceinline__ float fast_rsq(float x){ return __builtin_amdgcn_rsqf(x); }
static __device__ __forceinline__ float fast_rcp(float x){ return __builtin_amdgcn_rcpf(x); }

// full-rate VALU lane exchange via DPP
template<int CTRL>
static __device__ __forceinline__ float dpp_mov(float v) {
    return __int_as_float(__builtin_amdgcn_update_dpp(
        0, __float_as_int(v), CTRL, 0xF, 0xF, false));
}
// capsule reduce: sum over the 4 quad lanes (xor1 + xor2, quad_perm DPP)
static __device__ __forceinline__ float rsum_quad(float v) {
    v += dpp_mov<0xB1>(v);   // quad_perm [1,0,3,2] == xor1
    v += dpp_mov<0x4E>(v);   // quad_perm [2,3,0,1] == xor2
    return v;
}
// cross-capsule reduce: lanes at stride 4 within each 32-lane half
static __device__ __forceinline__ float rsum_caps(float v) {
    v += __shfl_xor(v, 4);
    v += dpp_mov<0x128>(v);  // row_ror:8 == xor8 (full-rate)
    v += __shfl_xor(v, 16);
    return v;
}
static __device__ __forceinline__ float rmax_caps(float v) {
    v = fmaxf(v, __shfl_xor(v, 4));
    v = fmaxf(v, dpp_mov<0x128>(v));
    v = fmaxf(v, __shfl_xor(v, 16));
    return v;
}

static __device__ __forceinline__ void cas(float& x, float& y) {
    float lo = fminf(x, y), hi = fmaxf(x, y);
    x = lo; y = hi;
}
// Batcher odd-even mergesort, 8 elements, 19 CAS
static __device__ __forceinline__ void sort8(float a[8]) {
    cas(a[0],a[1]); cas(a[2],a[3]); cas(a[4],a[5]); cas(a[6],a[7]);
    cas(a[0],a[2]); cas(a[1],a[3]); cas(a[4],a[6]); cas(a[5],a[7]);
    cas(a[1],a[2]); cas(a[5],a[6]);
    cas(a[0],a[4]); cas(a[2],a[6]); cas(a[2],a[4]);
    cas(a[1],a[5]); cas(a[3],a[7]); cas(a[3],a[5]);
    cas(a[1],a[2]); cas(a[3],a[4]); cas(a[5],a[6]);
}
// median of 16 values (a[]) plus self: b7/b8 order stats via merged-rank
// identity, then med3 clamp of self into the middle pair.
static __device__ __forceinline__ float med17(float a[16], float self) {
    sort8(a); sort8(a + 8);
    const float* u = a; const float* v = a + 8;
    float t7 =            fminf(u[7], v[0]);
    t7 = fmaxf(t7, fminf(u[6], v[1]));
    t7 = fmaxf(t7, fminf(u[5], v[2]));
    t7 = fmaxf(t7, fminf(u[4], v[3]));
    t7 = fmaxf(t7, fminf(u[3], v[4]));
    t7 = fmaxf(t7, fminf(u[2], v[5]));
    t7 = fmaxf(t7, fminf(u[1], v[6]));
    t7 = fmaxf(t7, fminf(u[0], v[7]));
    float t8 = fmaxf(u[0], v[0]);
    t8 = fmaxf(t8, fminf(u[7], v[1]));
    t8 = fmaxf(t8, fminf(u[6], v[2]));
    t8 = fmaxf(t8, fminf(u[5], v[3]));
    t8 = fmaxf(t8, fminf(u[4], v[4]));
    t8 = fmaxf(t8, fminf(u[3], v[5]));
    t8 = fmaxf(t8, fminf(u[2], v[6]));
    t8 = fmaxf(t8, fminf(u[1], v[7]));
    return __builtin_amdgcn_fmed3f(self, t7, t8);
}

// flag[0] = 1 if h is bf16, 0 if f32
__global__ void detect_dtype(const unsigned short* __restrict__ h, int* __restrict__ flag) {
    int l = threadIdx.x;
    float m = 0.f;
    for (int i = l; i < 1024; i += 64) {
        float v = bf2f1(h[i]);
        v = (v != v) ? 1e30f : fabsf(v);
        m = fmaxf(m, v);
    }
    #pragma unroll
    for (int off = 1; off < 64; off <<= 1) m = fmaxf(m, __shfl_xor(m, off));
    if (l == 0) flag[0] = (m < 1000.0f) ? 1 : 0;
}

template<bool BF>
__global__ __launch_bounds__(256)
void attn_fwd(const void* __restrict__ hraw,
              const int* __restrict__ nbr,
              const void* __restrict__ qry,
              const void* __restrict__ keyw,
              const int* __restrict__ iterat_p,
              const int* __restrict__ flag_p,
              void* __restrict__ out,
              int n_nodes)
{
    if (flag_p[0] != (BF ? 1 : 0)) return;  // uniform exit before any barrier

    const int tid  = threadIdx.x;
    const int wid  = tid >> 6;
    const int l    = tid & 63;
    const int sub  = l & 31;        // lane within the node's 32-lane group
    const int half = (l >> 5) & 1;  // which of the wave's 2 nodes
    const int k    = sub >> 2;      // capsule 0..7
    const int q4   = sub & 3;       // quad position: dims q4*4 .. q4*4+3

    int n = blockIdx.x * 8 + wid * 2 + half;
    if (n >= n_nodes) n = n_nodes - 1;  // duplicate work writes identical values

    __shared__ float qry_s[16 * QS];  // Q row-major
    __shared__ float kt_s [16 * QS];  // K^T
    {
        float qv = load1<BF>(qry, tid);
        float kv = load1<BF>(keyw, tid);
        int e = tid >> 4, f = tid & 15;
        qry_s[e * QS + f] = qv;
        kt_s [f * QS + e] = kv;
    }

    // neighbor indices: lanes 0-15 node A, 16-31 node B (upper half repeats)
    int nnb = blockIdx.x * 8 + wid * 2 + ((l >> 4) & 1);
    if (nnb >= n_nodes) nnb = n_nodes - 1;
    const int nbv = nbr[nnb * MN + (l & 15)];

    // ---- self row (4 dims/lane), per-capsule normalize ----
    float hp[4];
    if (BF) {
        const unsigned int* hw = (const unsigned int*)hraw + (size_t)n * (MD / 2);
        unsigned int w0 = hw[sub * 2], w1 = hw[sub * 2 + 1];
        hp[0] = lo_bf(w0); hp[1] = hi_bf(w0); hp[2] = lo_bf(w1); hp[3] = hi_bf(w1);
    } else {
        float4 t = ((const float4*)((const float*)hraw + (size_t)n * MD))[sub];
        hp[0] = t.x; hp[1] = t.y; hp[2] = t.z; hp[3] = t.w;
    }
    float ss = 0;
    #pragma unroll
    for (int i = 0; i < 4; ++i) ss = fmaf(hp[i], hp[i], ss);
    ss = rsum_quad(ss);
    float inv = fast_rsq(fmaxf(ss, 1e-24f));
    float hc[4];
    #pragma unroll
    for (int i = 0; i < 4; ++i) hc[i] = hp[i] * inv;

    __syncthreads();  // Q/K staging visible (the only barrier)

    // ---- issue all 16 neighbor-row loads early (SGPR idx, 32-bit voffset) ----
    uint2  rb[16];
    float4 rf[16];
    const unsigned sb = (unsigned)sub * (BF ? 8u : 16u);
    #pragma unroll
    for (int m = 0; m < MN; ++m) {
        int ia = __builtin_amdgcn_readlane(nbv, m);
        int ib = __builtin_amdgcn_readlane(nbv, m + 16);
        int idx = half ? ib : ia;
        if (BF) {
            unsigned off = ((unsigned)idx << 8) + sb;
            rb[m] = *(const uint2*)((const char*)hraw + off);
        } else {
            unsigned off = ((unsigned)idx << 9) + sb;
            rf[m] = *(const float4*)((const char*)hraw + off);
        }
    }

    // ---- broadcast hc chunks within quad (full-rate DPP, no LDS) ----
    float hcA[4][4];
    #pragma unroll
    for (int j = 0; j < 4; ++j) {
        hcA[0][j] = dpp_mov<0x00>(hc[j]);
        hcA[1][j] = dpp_mov<0x55>(hc[j]);
        hcA[2][j] = dpp_mov<0xAA>(hc[j]);
        hcA[3][j] = dpp_mov<0xFF>(hc[j]);
    }
    // kk[d] = sum_e hc[e] * K[e][d]  (reads K^T rows d = q4*4+i)
    float kk[4];
    #pragma unroll
    for (int i = 0; i < 4; ++i) {
        const float* row = &kt_s[(q4 * 4 + i) * QS];
        float acc = 0;
        #pragma unroll
        for (int r = 0; r < 4; ++r) {
            float4 kr = *(const float4*)(row + r * 4);
            acc = fmaf(hcA[r][0], kr.x, acc);
            acc = fmaf(hcA[r][1], kr.y, acc);
            acc = fmaf(hcA[r][2], kr.z, acc);
            acc = fmaf(hcA[r][3], kr.w, acc);
        }
        kk[i] = acc;
    }
    // w[e] = sum_f Q[e][f] * kk[f]  (reads Q rows e = q4*4+i)
    float kkA[4][4];
    #pragma unroll
    for (int j = 0; j < 4; ++j) {
        kkA[0][j] = dpp_mov<0x00>(kk[j]);
        kkA[1][j] = dpp_mov<0x55>(kk[j]);
        kkA[2][j] = dpp_mov<0xAA>(kk[j]);
        kkA[3][j] = dpp_mov<0xFF>(kk[j]);
    }
    float w[4];
    #pragma unroll
    for (int i = 0; i < 4; ++i) {
        const float* row = &qry_s[(q4 * 4 + i) * QS];
        float acc = 0;
        #pragma unroll
        for (int r = 0; r < 4; ++r) {
            float4 qr = *(const float4*)(row + r * 4);
            acc = fmaf(kkA[r][0], qr.x, acc);
            acc = fmaf(kkA[r][1], qr.y, acc);
            acc = fmaf(kkA[r][2], qr.z, acc);
            acc = fmaf(kkA[r][3], qr.w, acc);
        }
        w[i] = acc;
    }

    // ---- att: logit = hc . w  (== q . kk), softmax over capsules ----
    float lg = 0;
    #pragma unroll
    for (int i = 0; i < 4; ++i) lg = fmaf(hc[i], w[i], lg);
    float logit = rsum_quad(lg);
    float mx  = rmax_caps(logit);
    float ex  = __expf(logit - mx);
    float att = ex * fast_rcp(rsum_caps(ex));

    // ---- per-column (4 dims) sums + median-of-17 ----
    float nbs[4], mid[4];
    #pragma unroll
    for (int c = 0; c < 4; ++c) {
        float a[16];
        float sn = 0, s2 = 0;
        #pragma unroll
        for (int m = 0; m < 16; ++m) {
            float val;
            if (BF) {
                unsigned int wd = (c < 2) ? rb[m].x : rb[m].y;
                val = (c & 1) ? hi_bf(wd) : lo_bf(wd);
            } else {
                val = (c == 0) ? rf[m].x : (c == 1) ? rf[m].y : (c == 2) ? rf[m].z : rf[m].w;
            }
            a[m] = val;
            sn += val;
            s2  = fmaf(val, val, s2);
        }
        float self = hc[c];
        s2 = fmaf(self, self, s2);
        nbs[c] = sn;
        mid[c] = med17(a, self) * fast_rsq(fmaxf(s2, 1e-24f));
    }

    // diag[k] = (sum_m nb[m,k]) . w[k]
    float dgl = 0;
    #pragma unroll
    for (int i = 0; i < 4; ++i) dgl = fmaf(nbs[i], w[i], dgl);
    float dg = rsum_quad(dgl);

    // cov_d = sum_k diag[k]*(hc-mid)^2  (row-independent)
    float cv[4];
    #pragma unroll
    for (int i = 0; i < 4; ++i) {
        float t = hc[i] - mid[i];
        cv[i] = rsum_caps(dg * t * t);
    }

    // dets/left, exact NaN semantics (v_log(neg)=NaN -> 1e-6 fix, double log)
    float lsl = 0;
    #pragma unroll
    for (int i = 0; i < 4; ++i) {
        float lr = __logf(cv[i]);
        lr = (lr != lr) ? 1e-6f : lr;
        lsl += __logf(lr);
    }
    float ls   = rsum_quad(lsl);
    float dets = __expf(ls);
    const float coef = 5.822108e-7f;  // 1/sqrt((2*pi)^16 / 2)
    float left = coef * fast_rsq(dets + 1e-6f);

    // ---- iterative routing ----
    float ah[4], ix[4];
    #pragma unroll
    for (int i = 0; i < 4; ++i) ah[i] = att * hc[i];
    #pragma unroll
    for (int i = 0; i < 4; ++i) ix[i] = rsum_caps(ah[i]);

    const int iterat = iterat_p[0];
    for (int it = 0; it < iterat; ++it) {
        float rsl = 0;
        #pragma unroll
        for (int i = 0; i < 4; ++i) {
            float df = ix[i] - hc[i];
            rsl = fmaf(cv[i] * df, df, rsl);
        }
        float rs   = rsum_quad(rsl);
        float prob = left * __expf(-0.5f * rs);
        float p2   = rsum_caps(prob * prob);
        float pn   = prob * fast_rsq(fmaxf(p2, 1e-24f));
        pn = (pn != pn) ? 1e-6f : pn;
        float den = rsum_caps(att * pn);
        float num[4];
        #pragma unroll
        for (int i = 0; i < 4; ++i) num[i] = rsum_caps(pn * ah[i]);
        float rr = fast_rcp(den + 1e-9f);
        #pragma unroll
        for (int i = 0; i < 4; ++i) ix[i] = num[i] * rr;
    }

    // ---- x = normalize(ix) ----
    float xs = 0;
    #pragma unroll
    for (int i = 0; i < 4; ++i) xs = fmaf(ix[i], ix[i], xs);
    xs = rsum_quad(xs);
    float xinv = fast_rsq(fmaxf(xs, 1e-24f));

    if (BF) {
        if (sub < 4) {  // capsule-0 lanes write the 16 output dims (8B each)
            __hip_bfloat16 b0 = __float2bfloat16(ix[0] * xinv);
            __hip_bfloat16 b1 = __float2bfloat16(ix[1] * xinv);
            __hip_bfloat16 b2 = __float2bfloat16(ix[2] * xinv);
            __hip_bfloat16 b3 = __float2bfloat16(ix[3] * xinv);
            uint2 o;
            o.x = (unsigned)(*(unsigned short*)&b0) | ((unsigned)(*(unsigned short*)&b1) << 16);
            o.y = (unsigned)(*(unsigned short*)&b2) | ((unsigned)(*(unsigned short*)&b3) << 16);
            *(uint2*)((char*)out + (size_t)n * 32 + q4 * 8) = o;
        }
        if (q4 == 0) {
            __hip_bfloat16 ba = __float2bfloat16(att);
            ((unsigned short*)out)[(size_t)n_nodes * KD + (size_t)n * KC + k] =
                *(unsigned short*)&ba;
        }
    } else {
        if (sub < 4) {
            float4 o;
            o.x = ix[0] * xinv; o.y = ix[1] * xinv; o.z = ix[2] * xinv; o.w = ix[3] * xinv;
            *(float4*)((float*)out + (size_t)n * KD + q4 * 4) = o;
        }
        if (q4 == 0) ((float*)out)[(size_t)n_nodes * KD + (size_t)n * KC + k] = att;
    }
}

extern "C" void kernel_launch(void* const* d_in, const int* in_sizes, int n_in,
                              void* d_out, int out_size, void* d_ws, size_t ws_size,
                              hipStream_t stream) {
    const void* h    = d_in[0];
    const int*  nbr  = (const int*)d_in[1];
    const void* qry  = d_in[2];
    const void* keyw = (const void*)d_in[3];
    const int*  iterat_p = (const int*)d_in[4];

    int n_nodes = in_sizes[0] / MD;
    int* flag = (int*)d_ws;

    detect_dtype<<<1, 64, 0, stream>>>((const unsigned short*)h, flag);

    int blocks = (n_nodes + 7) / 8;  // 8 nodes per block (4 waves x 2)
    attn_fwd<true ><<<blocks, 256, 0, stream>>>(h, nbr, qry, keyw, iterat_p, flag, d_out, n_nodes);
    attn_fwd<false><<<blocks, 256, 0, stream>>>(h, nbr, qry, keyw, iterat_p, flag, d_out, n_nodes);
}